// Round 3
// baseline (364.089 us; speedup 1.0000x reference)
//
#include <hip/hip_runtime.h>

// WKV7 (RWKV-7) forward scan. T=2048, H=64, D=64.
// R3: same decomposition as R2 (1024 blocks x 64 threads; block = head x
// 4-row block; lane owns 4 state columns; DPP row-of-16 reductions), plus:
//  - __launch_bounds__(64, 1): grid gives only 1 wave/SIMD anyway, so let
//    the register allocator use ~256 VGPRs and KEEP the 8 prefetch buffers
//    resident (R2's VGPR=128 silently collapsed the prefetch -> 330 cyc/step
//    of exposed memory latency).
//  - uniform (SALU) per-step base addresses; only the lane column offset is
//    vector. Cuts ~12 VALU/step of 64-bit vector address math.

constexpr int T_LEN = 2048;
constexpr int DD    = 64;
constexpr int HD    = 64 * 64;   // 4096

struct Buf {
  float4 r, e, k, a, b;
  float vv;
};

__global__ __launch_bounds__(256)
void exp_kernel(const float4* __restrict__ w, float4* __restrict__ ew, int n4) {
  int i = blockIdx.x * blockDim.x + threadIdx.x;
  int stride = gridDim.x * blockDim.x;
  for (; i < n4; i += stride) {
    float4 x = w[i];
    float4 o;
    o.x = __expf(x.x); o.y = __expf(x.y); o.z = __expf(x.z); o.w = __expf(x.w);
    ew[i] = o;
  }
}

template<int CTRL>
__device__ __forceinline__ float dpp_add(float x) {
  int y = __builtin_amdgcn_update_dpp(0, __float_as_int(x), CTRL, 0xf, 0xf, true);
  return x + __int_as_float(y);
}

// Sum across the 16 lanes of a DPP row (all lanes end with the sum).
__device__ __forceinline__ float row16_reduce(float x) {
  x = dpp_add<0xB1>(x);    // quad_perm [1,0,3,2] : + lane^1
  x = dpp_add<0x4E>(x);    // quad_perm [2,3,0,1] : + lane^2
  x = dpp_add<0x141>(x);   // row_half_mirror    : + other quad
  x = dpp_add<0x140>(x);   // row_mirror         : + other half
  return x;
}

__global__ __launch_bounds__(64, 1)
void wkv7_scan(const float* __restrict__ R, const float* __restrict__ EW,
               const float* __restrict__ K, const float* __restrict__ V,
               const float* __restrict__ A, const float* __restrict__ B,
               const float* __restrict__ S0, float* __restrict__ X,
               float* __restrict__ SOUT)
{
  const int blk = blockIdx.x;          // 0..1023
  // XCD co-location: 8 whole heads (16 row-blocks each) per XCD for L2 reuse.
  const int xcd = blk & 7;
  const int m   = blk >> 3;            // 0..127
  const int h   = xcd * 8 + (m & 7);   // head 0..63
  const int br  = m >> 3;              // row block 0..15

  const int lane = threadIdx.x;        // 0..63
  const int cg   = lane & 15;          // column group -> cols [cg*4, cg*4+4)
  const int rl   = lane >> 4;          // local row 0..3
  const int row  = br * 4 + rl;        // 0..63
  const int c0   = cg * 4;

  const int vecoff = h * DD + c0;      // lane offset for per-step column vectors
  const int voff   = h * DD + row;     // lane offset for v / x

  float4 s = *(const float4*)(S0 + (size_t)h * DD * DD + row * DD + c0);

  auto load = [&](Buf& bf, int t) {
    // (base + t*HD) stays uniform (SGPR); vecoff/voff are the only VGPR parts.
    const size_t o = (size_t)t * HD;
    bf.r  = *(const float4*)(R  + o + vecoff);
    bf.e  = *(const float4*)(EW + o + vecoff);
    bf.k  = *(const float4*)(K  + o + vecoff);
    bf.a  = *(const float4*)(A  + o + vecoff);
    bf.b  = *(const float4*)(B  + o + vecoff);
    bf.vv = V[o + voff];
  };

  auto step = [&](const Buf& c, int t) {
    // sa partial over this lane's 4 cols (2 independent chains, depth 2)
    float p0 = fmaf(s.z, c.a.z, s.x * c.a.x);
    float p1 = fmaf(s.w, c.a.w, s.y * c.a.y);
    float sa = row16_reduce(p0 + p1);

    const float vv = c.vv;
    s.x = fmaf(s.x, c.e.x, fmaf(vv, c.k.x, sa * c.b.x));
    s.y = fmaf(s.y, c.e.y, fmaf(vv, c.k.y, sa * c.b.y));
    s.z = fmaf(s.z, c.e.z, fmaf(vv, c.k.z, sa * c.b.z));
    s.w = fmaf(s.w, c.e.w, fmaf(vv, c.k.w, sa * c.b.w));

    float y0 = fmaf(s.z, c.r.z, s.x * c.r.x);
    float y1 = fmaf(s.w, c.r.w, s.y * c.r.y);
    float y  = row16_reduce(y0 + y1);
    // all 16 lanes of a row group write the same value to the same address.
    X[(size_t)t * HD + voff] = y;
  };

  Buf A0, A1, A2, A3, B0, B1, B2, B3;
  load(A0, 0); load(A1, 1); load(A2, 2); load(A3, 3);

  for (int t = 0; t < T_LEN; t += 8) {
    load(B0, (t + 4) & (T_LEN - 1));  step(A0, t);
    load(B1, (t + 5) & (T_LEN - 1));  step(A1, t + 1);
    load(B2, (t + 6) & (T_LEN - 1));  step(A2, t + 2);
    load(B3, (t + 7) & (T_LEN - 1));  step(A3, t + 3);
    load(A0, (t + 8) & (T_LEN - 1));  step(B0, t + 4);
    load(A1, (t + 9) & (T_LEN - 1));  step(B1, t + 5);
    load(A2, (t + 10) & (T_LEN - 1)); step(B2, t + 6);
    load(A3, (t + 11) & (T_LEN - 1)); step(B3, t + 7);
  }

  *(float4*)(SOUT + (size_t)h * DD * DD + row * DD + c0) = s;
}

extern "C" void kernel_launch(void* const* d_in, const int* in_sizes, int n_in,
                              void* d_out, int out_size, void* d_ws, size_t ws_size,
                              hipStream_t stream) {
  // setup_inputs order: seq_length, r, w, k, v, a, b, state2
  const float* r  = (const float*)d_in[1];
  const float* w  = (const float*)d_in[2];
  const float* k  = (const float*)d_in[3];
  const float* v  = (const float*)d_in[4];
  const float* a  = (const float*)d_in[5];
  const float* b  = (const float*)d_in[6];
  const float* s0 = (const float*)d_in[7];

  float* x    = (float*)d_out;                     // (T, H, 1, D)
  float* sout = x + (size_t)T_LEN * HD;            // (H, D, D)

  float* ew = (float*)d_ws;
  (void)ws_size; (void)in_sizes; (void)n_in;

  int n4 = T_LEN * HD / 4;
  hipLaunchKernelGGL(exp_kernel, dim3(1024), dim3(256), 0, stream,
                     (const float4*)w, (float4*)ew, n4);
  hipLaunchKernelGGL(wkv7_scan, dim3(1024), dim3(64), 0, stream,
                     r, ew, k, v, a, b, s0, x, sout);
}

// Round 4
// 362.503 us; speedup vs baseline: 1.0044x; 1.0044x over previous
//
#include <hip/hip_runtime.h>

// WKV7 (RWKV-7) forward scan. T=2048, H=64, D=64.
// R4: same decomposition as R2/R3 (1024 blocks x 64 threads; block = head x
// 4-row block; lane owns 4 state cols; DPP row-of-16 reductions). New:
//  - HAND PIPELINE: asm volatile global_load (saddr + uniform-VGPR-offset)
//    into 8 named buffers, prefetch distance 8 steps; counted
//    s_waitcnt vmcnt(42) (=6*7 newer loads) + sched_barrier(0) before each
//    consume (rule #18). R2/R3 showed hipcc sinks plain loads to use-point
//    (VGPR stayed 128), exposing ~330 cyc/step of memory latency.

typedef float f32x4 __attribute__((ext_vector_type(4)));

constexpr int T_LEN = 2048;
constexpr int DD    = 64;
constexpr int HD    = 64 * 64;   // 4096

struct Buf { f32x4 r, e, k, a, b; float vv; };

__global__ __launch_bounds__(256)
void exp_kernel(const float4* __restrict__ w, float4* __restrict__ ew, int n4) {
  int i = blockIdx.x * blockDim.x + threadIdx.x;
  int stride = gridDim.x * blockDim.x;
  for (; i < n4; i += stride) {
    float4 x = w[i];
    float4 o;
    o.x = __expf(x.x); o.y = __expf(x.y); o.z = __expf(x.z); o.w = __expf(x.w);
    ew[i] = o;
  }
}

template<int CTRL>
__device__ __forceinline__ float dpp_add(float x) {
  int y = __builtin_amdgcn_update_dpp(0, __float_as_int(x), CTRL, 0xf, 0xf, true);
  return x + __int_as_float(y);
}

// Sum across the 16 lanes of a DPP row (all lanes end with the sum).
__device__ __forceinline__ float row16_reduce(float x) {
  x = dpp_add<0xB1>(x);    // quad_perm [1,0,3,2] : + lane^1
  x = dpp_add<0x4E>(x);    // quad_perm [2,3,0,1] : + lane^2
  x = dpp_add<0x141>(x);   // row_half_mirror    : + other quad
  x = dpp_add<0x140>(x);   // row_mirror         : + other half
  return x;
}

// Volatile asm loads: compiler cannot sink these; base is uniform (SGPR pair),
// voffb is a loop-invariant per-lane byte offset (VGPR).
__device__ __forceinline__ void gload4(f32x4& d, const float* base, int voffb) {
  asm volatile("global_load_dwordx4 %0, %1, %2"
               : "=v"(d) : "v"(voffb), "s"(base) : "memory");
}
__device__ __forceinline__ void gload1(float& d, const float* base, int voffb) {
  asm volatile("global_load_dword %0, %1, %2"
               : "=v"(d) : "v"(voffb), "s"(base) : "memory");
}
__device__ __forceinline__ void gstore1(float y, float* base, int voffb) {
  asm volatile("global_store_dword %0, %1, %2"
               :: "v"(voffb), "v"(y), "s"(base) : "memory");
}

__global__ __launch_bounds__(64, 1)
void wkv7_scan(const float* __restrict__ R, const float* __restrict__ EW,
               const float* __restrict__ K, const float* __restrict__ V,
               const float* __restrict__ A, const float* __restrict__ B,
               const float* __restrict__ S0, float* __restrict__ X,
               float* __restrict__ SOUT)
{
  const int blk = blockIdx.x;          // 0..1023
  // XCD co-location: 8 whole heads (16 row-blocks each) per XCD for L2 reuse.
  const int xcd = blk & 7;
  const int m   = blk >> 3;            // 0..127
  const int h   = xcd * 8 + (m & 7);   // head 0..63
  const int br  = m >> 3;              // row block 0..15

  const int lane = threadIdx.x;        // 0..63
  const int cg   = lane & 15;          // cols [cg*4, cg*4+4)
  const int rl   = lane >> 4;          // local row 0..3
  const int row  = br * 4 + rl;        // 0..63
  const int c0   = cg * 4;

  const int offb  = (h * DD + c0) * 4;   // byte offset, column vectors
  const int offvb = (h * DD + row) * 4;  // byte offset, v / x

  f32x4 s;
  {
    const f32x4* sp = (const f32x4*)(S0 + (size_t)h * DD * DD + row * DD + c0);
    s = *sp;
  }

  auto load = [&](Buf& bf, int t) {
    const size_t o = (size_t)t * HD;     // uniform -> SGPR adds
    gload4(bf.r, R  + o, offb);
    gload4(bf.e, EW + o, offb);
    gload4(bf.k, K  + o, offb);
    gload4(bf.a, A  + o, offb);
    gload4(bf.b, B  + o, offb);
    gload1(bf.vv, V + o, offvb);
  };

  auto step = [&](const Buf& c, int t) {
    // Buffer t was loaded 8 steps ago; 7 newer buffers * 6 loads = 42 may
    // remain outstanding. Counted wait, never 0 (T4).
    asm volatile("s_waitcnt vmcnt(42)" ::: "memory");
    __builtin_amdgcn_sched_barrier(0);   // rule #18: pin consumers below wait

    float p0 = fmaf(s[2], c.a[2], s[0] * c.a[0]);
    float p1 = fmaf(s[3], c.a[3], s[1] * c.a[1]);
    float sa = row16_reduce(p0 + p1);

    const float vv = c.vv;
    s[0] = fmaf(s[0], c.e[0], fmaf(vv, c.k[0], sa * c.b[0]));
    s[1] = fmaf(s[1], c.e[1], fmaf(vv, c.k[1], sa * c.b[1]));
    s[2] = fmaf(s[2], c.e[2], fmaf(vv, c.k[2], sa * c.b[2]));
    s[3] = fmaf(s[3], c.e[3], fmaf(vv, c.k[3], sa * c.b[3]));

    float y0 = fmaf(s[2], c.r[2], s[0] * c.r[0]);
    float y1 = fmaf(s[3], c.r[3], s[1] * c.r[1]);
    float y  = row16_reduce(y0 + y1);
    // 16 lanes of a row group store the same value to the same address.
    gstore1(y, X + (size_t)t * HD, offvb);
  };

  Buf B0, B1, B2, B3, B4, B5, B6, B7;
  load(B0, 0); load(B1, 1); load(B2, 2); load(B3, 3);
  load(B4, 4); load(B5, 5); load(B6, 6); load(B7, 7);

  for (int t = 0; t < T_LEN; t += 8) {
    step(B0, t    ); load(B0, (t +  8) & (T_LEN - 1));
    step(B1, t + 1); load(B1, (t +  9) & (T_LEN - 1));
    step(B2, t + 2); load(B2, (t + 10) & (T_LEN - 1));
    step(B3, t + 3); load(B3, (t + 11) & (T_LEN - 1));
    step(B4, t + 4); load(B4, (t + 12) & (T_LEN - 1));
    step(B5, t + 5); load(B5, (t + 13) & (T_LEN - 1));
    step(B6, t + 6); load(B6, (t + 14) & (T_LEN - 1));
    step(B7, t + 7); load(B7, (t + 15) & (T_LEN - 1));
  }

  *(f32x4*)(SOUT + (size_t)h * DD * DD + row * DD + c0) = s;
}

extern "C" void kernel_launch(void* const* d_in, const int* in_sizes, int n_in,
                              void* d_out, int out_size, void* d_ws, size_t ws_size,
                              hipStream_t stream) {
  // setup_inputs order: seq_length, r, w, k, v, a, b, state2
  const float* r  = (const float*)d_in[1];
  const float* w  = (const float*)d_in[2];
  const float* k  = (const float*)d_in[3];
  const float* v  = (const float*)d_in[4];
  const float* a  = (const float*)d_in[5];
  const float* b  = (const float*)d_in[6];
  const float* s0 = (const float*)d_in[7];

  float* x    = (float*)d_out;                     // (T, H, 1, D)
  float* sout = x + (size_t)T_LEN * HD;            // (H, D, D)

  float* ew = (float*)d_ws;
  (void)ws_size; (void)in_sizes; (void)n_in;

  int n4 = T_LEN * HD / 4;
  hipLaunchKernelGGL(exp_kernel, dim3(1024), dim3(256), 0, stream,
                     (const float4*)w, (float4*)ew, n4);
  hipLaunchKernelGGL(wkv7_scan, dim3(1024), dim3(64), 0, stream,
                     r, ew, k, v, a, b, s0, x, sout);
}

// Round 5
// 356.367 us; speedup vs baseline: 1.0217x; 1.0172x over previous
//
#include <hip/hip_runtime.h>

// WKV7 (RWKV-7) forward scan. T=2048, H=64, D=64.
// R5: 1024 blocks x 64 threads (block = head x 4-row block; lane owns 4 state
// cols; DPP row-of-16 reductions). Memory pipeline rebuilt around an 8-slot
// global_load_lds ring (T3/T4):
//   - stage t -> LDS slot t&7 (6 x global_load_lds dword, no VGPR cost)
//   - counted s_waitcnt vmcnt(36): exactly 36 loads are newer than stage t+1
//   - LDS -> regs one step ahead (2 named Buf registers, 42 VGPRs)
//   - s_waitcnt lgkmcnt(6) + sched_barrier(0) before compute (rule #18)
// R4 failed because 8 reg-resident buffers (168 VGPRs) made the allocator
// spill in-flight load dests (VGPR=96, VALUBusy 16%); LDS ring sidesteps it.

typedef float f32x4 __attribute__((ext_vector_type(4)));

constexpr int T_LEN = 2048;
constexpr int DD    = 64;
constexpr int HD    = 64 * 64;   // 4096

#define AS1 __attribute__((address_space(1)))
#define AS3 __attribute__((address_space(3)))

struct Buf { f32x4 r, e, k, a, b; float vv; };

__global__ __launch_bounds__(256)
void exp_kernel(const float4* __restrict__ w, float4* __restrict__ ew, int n4) {
  int i = blockIdx.x * blockDim.x + threadIdx.x;
  int stride = gridDim.x * blockDim.x;
  for (; i < n4; i += stride) {
    float4 x = w[i];
    float4 o;
    o.x = __expf(x.x); o.y = __expf(x.y); o.z = __expf(x.z); o.w = __expf(x.w);
    ew[i] = o;
  }
}

template<int CTRL>
__device__ __forceinline__ float dpp_add(float x) {
  int y = __builtin_amdgcn_update_dpp(0, __float_as_int(x), CTRL, 0xf, 0xf, true);
  return x + __int_as_float(y);
}

// Sum across the 16 lanes of a DPP row (all lanes end with the sum).
__device__ __forceinline__ float row16_reduce(float x) {
  x = dpp_add<0xB1>(x);    // quad_perm [1,0,3,2] : + lane^1
  x = dpp_add<0x4E>(x);    // quad_perm [2,3,0,1] : + lane^2
  x = dpp_add<0x141>(x);   // row_half_mirror    : + other quad
  x = dpp_add<0x140>(x);   // row_mirror         : + other half
  return x;
}

__device__ __forceinline__ void gload_lds(const float* g, const float* l) {
  __builtin_amdgcn_global_load_lds((const AS1 unsigned*)g, (AS3 unsigned*)l, 4, 0, 0);
}

__global__ __launch_bounds__(64, 1)
void wkv7_scan(const float* __restrict__ R, const float* __restrict__ EW,
               const float* __restrict__ K, const float* __restrict__ V,
               const float* __restrict__ A, const float* __restrict__ B,
               const float* __restrict__ S0, float* __restrict__ X,
               float* __restrict__ SOUT)
{
  // 8 slots x (5 vectors + v) x 64 floats = 3072 floats = 12 KB
  __shared__ float smem[3072];

  const int blk = blockIdx.x;          // 0..1023
  // XCD co-location: 8 whole heads (16 row-blocks each) per XCD for L2 reuse.
  const int xcd = blk & 7;
  const int m   = blk >> 3;            // 0..127
  const int h   = xcd * 8 + (m & 7);   // head 0..63
  const int br  = m >> 3;              // row block 0..15

  const int lane = threadIdx.x;        // 0..63
  const int cg   = lane & 15;          // cols [cg*4, cg*4+4)
  const int rl   = lane >> 4;          // local row 0..3
  const int row  = br * 4 + rl;        // 0..63
  const int c0   = cg * 4;

  const int laneoff = h * DD + lane;   // per-lane global offset, all 6 arrays

  const unsigned lb  = (unsigned)(uintptr_t)(AS3 float*)&smem[0];
  const unsigned vab = lb + (unsigned)(cg * 16);   // vector-read base
  const unsigned vvb = lb + (unsigned)(row * 4);   // v-read base (offset:1280)

  int yoff = (h * DD + row) * 4;       // byte offset into X, advances by HD*4

  f32x4 s;
  {
    const f32x4* sp = (const f32x4*)(S0 + (size_t)h * DD * DD + row * DD + c0);
    s = *sp;
  }

  auto stage = [&](int tt, int slot) {
    const size_t o = (size_t)tt * HD + laneoff;
    const float* l = &smem[slot * 384];
    gload_lds(R  + o, l);
    gload_lds(EW + o, l + 64);
    gload_lds(K  + o, l + 128);
    gload_lds(A  + o, l + 192);
    gload_lds(B  + o, l + 256);
    gload_lds(V  + o, l + 320);
  };

  auto lds_read = [&](Buf& d, int slot) {
    unsigned va = vab + (unsigned)(slot * 1536);
    unsigned vv = vvb + (unsigned)(slot * 1536);
    asm volatile(
      "ds_read_b128 %0, %6\n\t"
      "ds_read_b128 %1, %6 offset:256\n\t"
      "ds_read_b128 %2, %6 offset:512\n\t"
      "ds_read_b128 %3, %6 offset:768\n\t"
      "ds_read_b128 %4, %6 offset:1024\n\t"
      "ds_read_b32  %5, %7 offset:1280"
      : "=&v"(d.r), "=&v"(d.e), "=&v"(d.k), "=&v"(d.a), "=&v"(d.b), "=&v"(d.vv)
      : "v"(va), "v"(vv) : "memory");
  };

  auto body = [&](Buf& cur, Buf& nxt, int t) {
    // Stage t+1 resident? 36 loads (stages t+2..t+7) are strictly newer than
    // stage t+1's; waiting to <=36 outstanding guarantees stage t+1 landed.
    asm volatile("s_waitcnt vmcnt(36)" ::: "memory");
    lds_read(nxt, (t + 1) & 7);
    // cur's 6 ds_reads (issued last body) are the only DS ops older than the
    // 6 just issued.
    asm volatile("s_waitcnt lgkmcnt(6)" ::: "memory");
    __builtin_amdgcn_sched_barrier(0);   // rule #18: pin consumers below wait

    float p0 = fmaf(s[2], cur.a[2], s[0] * cur.a[0]);
    float p1 = fmaf(s[3], cur.a[3], s[1] * cur.a[1]);
    float sa = row16_reduce(p0 + p1);

    const float vv = cur.vv;
    s[0] = fmaf(s[0], cur.e[0], fmaf(vv, cur.k[0], sa * cur.b[0]));
    s[1] = fmaf(s[1], cur.e[1], fmaf(vv, cur.k[1], sa * cur.b[1]));
    s[2] = fmaf(s[2], cur.e[2], fmaf(vv, cur.k[2], sa * cur.b[2]));
    s[3] = fmaf(s[3], cur.e[3], fmaf(vv, cur.k[3], sa * cur.b[3]));

    float y0 = fmaf(s[2], cur.r[2], s[0] * cur.r[0]);
    float y1 = fmaf(s[3], cur.r[3], s[1] * cur.r[1]);
    float y  = row16_reduce(y0 + y1);
    // 16 lanes of a row group store the same value to the same address.
    asm volatile("global_store_dword %0, %1, %2"
                 :: "v"(yoff), "v"(y), "s"(X) : "memory");
    yoff += HD * 4;

    stage((t + 8) & (T_LEN - 1), t & 7);  // refill freed slot (dummy at tail)
  };

  // Prologue: fill the ring (stages 0..7, in order), then regs for step 0.
  for (int i = 0; i < 8; ++i) {
    stage(i, i);
    __builtin_amdgcn_sched_barrier(0);   // keep stage issue order = count order
  }
  asm volatile("s_waitcnt vmcnt(42)" ::: "memory");  // stage 0 done (42 newer)

  Buf RA, RB;
  lds_read(RA, 0);

  for (int t = 0; t < T_LEN; t += 2) {
    body(RA, RB, t);
    body(RB, RA, t + 1);
  }

  *(f32x4*)(SOUT + (size_t)h * DD * DD + row * DD + c0) = s;
}

extern "C" void kernel_launch(void* const* d_in, const int* in_sizes, int n_in,
                              void* d_out, int out_size, void* d_ws, size_t ws_size,
                              hipStream_t stream) {
  // setup_inputs order: seq_length, r, w, k, v, a, b, state2
  const float* r  = (const float*)d_in[1];
  const float* w  = (const float*)d_in[2];
  const float* k  = (const float*)d_in[3];
  const float* v  = (const float*)d_in[4];
  const float* a  = (const float*)d_in[5];
  const float* b  = (const float*)d_in[6];
  const float* s0 = (const float*)d_in[7];

  float* x    = (float*)d_out;                     // (T, H, 1, D)
  float* sout = x + (size_t)T_LEN * HD;            // (H, D, D)

  float* ew = (float*)d_ws;
  (void)ws_size; (void)in_sizes; (void)n_in;

  int n4 = T_LEN * HD / 4;
  hipLaunchKernelGGL(exp_kernel, dim3(1024), dim3(256), 0, stream,
                     (const float4*)w, (float4*)ew, n4);
  hipLaunchKernelGGL(wkv7_scan, dim3(1024), dim3(64), 0, stream,
                     r, ew, k, v, a, b, s0, x, sout);
}